// Round 2
// baseline (662.302 us; speedup 1.0000x reference)
//
#include <hip/hip_runtime.h>

#define HIDDEN 1024
#define NHEADS 16
#define HEAD   64
#define BATCH  4
#define SEQ    2048
#define BS     (BATCH*SEQ)   // 8192
#define H3     (3*HIDDEN)    // 3072

typedef unsigned short u16;
typedef unsigned int   u32;
typedef __bf16 bf16x8 __attribute__((ext_vector_type(8)));
typedef float  f32x4  __attribute__((ext_vector_type(4)));

__device__ __forceinline__ u16 f2bf(float f) {
    union { float f; u32 u; } v; v.f = f;
    u32 u = v.u;
    u32 r = u + 0x7FFFu + ((u >> 16) & 1u);
    return (u16)(r >> 16);
}

// ---------------------------------------------------------------------------
// GEMM1: qkv = x @ qkv_w + qkv_b  ->  Q (x0.125) / K / V in [B,H,S,64] bf16
// ---------------------------------------------------------------------------
__global__ __launch_bounds__(256) void qkv_gemm(
    const float* __restrict__ x, const float* __restrict__ w,
    const float* __restrict__ bias,
    u16* __restrict__ q_ws, u16* __restrict__ k_ws, u16* __restrict__ v_ws)
{
    __shared__ u16 a_lds[128][40];   // [m][k] bf16, +8 pad
    __shared__ u16 b_lds[128][40];   // [n][k] bf16 (transposed), +8 pad

    const int t    = threadIdx.x;
    const int m0   = blockIdx.y * 128;
    const int n0   = blockIdx.x * 128;
    const int lane = t & 63, wv = t >> 6;
    const int lr   = lane & 15, lg = lane >> 4;
    const int wr   = wv >> 1, wc = wv & 1;

    f32x4 acc[4][4];
#pragma unroll
    for (int m = 0; m < 4; m++)
#pragma unroll
        for (int n = 0; n < 4; n++)
#pragma unroll
            for (int r = 0; r < 4; r++) acc[m][n][r] = 0.f;

    for (int kk = 0; kk < HIDDEN; kk += 32) {
        __syncthreads();
        // stage A [128][32] fp32 -> bf16
#pragma unroll
        for (int p = 0; p < 4; p++) {
            int r  = (t >> 3) + p * 32;
            int c4 = (t & 7) * 4;
            const float4 vv = *(const float4*)&x[(size_t)(m0 + r) * HIDDEN + kk + c4];
            ushort4 uu;
            uu.x = f2bf(vv.x); uu.y = f2bf(vv.y); uu.z = f2bf(vv.z); uu.w = f2bf(vv.w);
            *(ushort4*)&a_lds[r][c4] = uu;
        }
        // stage B [32][128] fp32 -> transposed bf16 [128][32]
#pragma unroll
        for (int p = 0; p < 4; p++) {
            int kr = (t >> 5) + p * 8;
            int n4 = (t & 31) * 4;
            const float4 vv = *(const float4*)&w[(size_t)(kk + kr) * H3 + n0 + n4];
            b_lds[n4 + 0][kr] = f2bf(vv.x);
            b_lds[n4 + 1][kr] = f2bf(vv.y);
            b_lds[n4 + 2][kr] = f2bf(vv.z);
            b_lds[n4 + 3][kr] = f2bf(vv.w);
        }
        __syncthreads();

        bf16x8 af[4], bfr[4];
#pragma unroll
        for (int m = 0; m < 4; m++)
            af[m] = *(const bf16x8*)&a_lds[wr * 64 + m * 16 + lr][lg * 8];
#pragma unroll
        for (int n = 0; n < 4; n++)
            bfr[n] = *(const bf16x8*)&b_lds[wc * 64 + n * 16 + lr][lg * 8];
#pragma unroll
        for (int m = 0; m < 4; m++)
#pragma unroll
            for (int n = 0; n < 4; n++)
                acc[m][n] = __builtin_amdgcn_mfma_f32_16x16x32_bf16(af[m], bfr[n], acc[m][n], 0, 0, 0);
    }

    // epilogue: route columns to Q/K/V in [B,H,S,64]
#pragma unroll
    for (int m = 0; m < 4; m++) {
#pragma unroll
        for (int n = 0; n < 4; n++) {
#pragma unroll
            for (int r = 0; r < 4; r++) {
                int row = m0 + wr * 64 + m * 16 + lg * 4 + r;
                int col = n0 + wc * 64 + n * 16 + lr;
                float val = acc[m][n][r] + bias[col];
                int which = col >> 10;
                int cid   = col & 1023;
                int h = cid >> 6, d = cid & 63;
                int b = row >> 11, s = row & 2047;
                size_t idx = ((size_t)(b * NHEADS + h) * SEQ + s) * HEAD + d;
                if (which == 0)      q_ws[idx] = f2bf(val * 0.125f);   // fold 1/sqrt(64)
                else if (which == 1) k_ws[idx] = f2bf(val);
                else                 v_ws[idx] = f2bf(val);
            }
        }
    }
}

// ---------------------------------------------------------------------------
// Causal flash attention: one block per (b*h, q-tile of 64 rows)
// ---------------------------------------------------------------------------
__global__ __launch_bounds__(256) void attn_kernel(
    const u16* __restrict__ q_ws, const u16* __restrict__ k_ws,
    const u16* __restrict__ v_ws, u16* __restrict__ ctx_ws)
{
    __shared__ u16 k_lds[64][72];    // [kcol][d], +8 pad
    __shared__ u16 vt_lds[64][72];   // [d][kcol] (transposed), +8 pad
    __shared__ u16 p_lds[4][16][72]; // per-wave P tile [qrow][kcol]

    const int t    = threadIdx.x;
    const int qt   = blockIdx.x & 31;
    const int bh   = blockIdx.x >> 5;
    const int lane = t & 63, wv = t >> 6;
    const int lr   = lane & 15, lg = lane >> 4;

    // Q fragments for this wave's 16 rows (Q already scaled by 1/8)
    const int qr0 = qt * 64 + wv * 16;
    bf16x8 qa[2];
#pragma unroll
    for (int ks = 0; ks < 2; ks++)
        qa[ks] = *(const bf16x8*)&q_ws[((size_t)bh * SEQ + qr0 + lr) * HEAD + ks * 32 + lg * 8];

    f32x4 acc_o[4];
#pragma unroll
    for (int df = 0; df < 4; df++)
#pragma unroll
        for (int r = 0; r < 4; r++) acc_o[df][r] = 0.f;
    float m_run[4], l_run[4];
#pragma unroll
    for (int r = 0; r < 4; r++) { m_run[r] = -3e38f; l_run[r] = 0.f; }

    for (int kt = 0; kt <= qt; kt++) {
        __syncthreads();
        // stage K tile [64][64]
#pragma unroll
        for (int p = 0; p < 2; p++) {
            int r   = (t >> 3) + p * 32;
            int seg = (t & 7) * 8;
            uint4 vv = *(const uint4*)&k_ws[((size_t)bh * SEQ + kt * 64 + r) * HEAD + seg];
            *(uint4*)&k_lds[r][seg] = vv;
        }
        // stage V transposed [d][kcol]
        {
            int kr = t >> 2;
            int d0 = (t & 3) * 16;
            u16 tmp[16];
            *(uint4*)&tmp[0] = *(const uint4*)&v_ws[((size_t)bh * SEQ + kt * 64 + kr) * HEAD + d0];
            *(uint4*)&tmp[8] = *(const uint4*)&v_ws[((size_t)bh * SEQ + kt * 64 + kr) * HEAD + d0 + 8];
#pragma unroll
            for (int i = 0; i < 16; i++) vt_lds[d0 + i][kr] = tmp[i];
        }
        __syncthreads();

        // QK^T : S[16 q][64 k]
        f32x4 s_acc[4];
#pragma unroll
        for (int nf = 0; nf < 4; nf++) {
#pragma unroll
            for (int r = 0; r < 4; r++) s_acc[nf][r] = 0.f;
#pragma unroll
            for (int ks = 0; ks < 2; ks++) {
                bf16x8 kb = *(const bf16x8*)&k_lds[nf * 16 + lr][ks * 32 + lg * 8];
                s_acc[nf] = __builtin_amdgcn_mfma_f32_16x16x32_bf16(qa[ks], kb, s_acc[nf], 0, 0, 0);
            }
        }

        // causal mask on diagonal tile (strict: k > q masked)
        if (kt == qt) {
#pragma unroll
            for (int nf = 0; nf < 4; nf++)
#pragma unroll
                for (int r = 0; r < 4; r++) {
                    int gq = wv * 16 + lg * 4 + r;
                    int gk = nf * 16 + lr;
                    if (gk > gq) s_acc[nf][r] = -1e9f;
                }
        }

        // online softmax (rows spread: reduce over 16-lane group = k columns)
        float p[4][4];
#pragma unroll
        for (int r = 0; r < 4; r++) {
            float mx = fmaxf(fmaxf(s_acc[0][r], s_acc[1][r]), fmaxf(s_acc[2][r], s_acc[3][r]));
#pragma unroll
            for (int off = 8; off >= 1; off >>= 1)
                mx = fmaxf(mx, __shfl_xor(mx, off));
            float m_new = fmaxf(m_run[r], mx);
            float sc = __expf(m_run[r] - m_new);
            float rs = 0.f;
#pragma unroll
            for (int nf = 0; nf < 4; nf++) {
                p[nf][r] = __expf(s_acc[nf][r] - m_new);
                rs += p[nf][r];
            }
#pragma unroll
            for (int off = 8; off >= 1; off >>= 1)
                rs += __shfl_xor(rs, off);
            l_run[r] = l_run[r] * sc + rs;
            m_run[r] = m_new;
#pragma unroll
            for (int df = 0; df < 4; df++) acc_o[df][r] *= sc;
        }

        // P -> LDS (D-layout) then reload as A-fragments
#pragma unroll
        for (int nf = 0; nf < 4; nf++)
#pragma unroll
            for (int r = 0; r < 4; r++)
                p_lds[wv][lg * 4 + r][nf * 16 + lr] = f2bf(p[nf][r]);
        __syncthreads();

        bf16x8 pa[2];
#pragma unroll
        for (int ks = 0; ks < 2; ks++)
            pa[ks] = *(const bf16x8*)&p_lds[wv][lr][ks * 32 + lg * 8];
#pragma unroll
        for (int df = 0; df < 4; df++) {
#pragma unroll
            for (int ks = 0; ks < 2; ks++) {
                bf16x8 vb = *(const bf16x8*)&vt_lds[df * 16 + lr][ks * 32 + lg * 8];
                acc_o[df] = __builtin_amdgcn_mfma_f32_16x16x32_bf16(pa[ks], vb, acc_o[df], 0, 0, 0);
            }
        }
    }

    // epilogue: ctx [B,S, h*64+d] bf16
    const int b = bh >> 4, h = bh & 15;
#pragma unroll
    for (int r = 0; r < 4; r++) {
        float inv = 1.f / l_run[r];
        int s = qt * 64 + wv * 16 + lg * 4 + r;
#pragma unroll
        for (int df = 0; df < 4; df++) {
            int d = df * 16 + lr;
            ctx_ws[((size_t)(b * SEQ + s)) * HIDDEN + h * HEAD + d] = f2bf(acc_o[df][r] * inv);
        }
    }
}

// ---------------------------------------------------------------------------
// GEMM2: out = ctx(bf16) @ out_w + out_b   (fp32 out)
// ---------------------------------------------------------------------------
__global__ __launch_bounds__(256) void out_gemm(
    const u16* __restrict__ ctx, const float* __restrict__ w,
    const float* __restrict__ bias, float* __restrict__ out)
{
    __shared__ u16 a_lds[128][40];
    __shared__ u16 b_lds[128][40];

    const int t    = threadIdx.x;
    const int m0   = blockIdx.y * 128;
    const int n0   = blockIdx.x * 128;
    const int lane = t & 63, wv = t >> 6;
    const int lr   = lane & 15, lg = lane >> 4;
    const int wr   = wv >> 1, wc = wv & 1;

    f32x4 acc[4][4];
#pragma unroll
    for (int m = 0; m < 4; m++)
#pragma unroll
        for (int n = 0; n < 4; n++)
#pragma unroll
            for (int r = 0; r < 4; r++) acc[m][n][r] = 0.f;

    for (int kk = 0; kk < HIDDEN; kk += 32) {
        __syncthreads();
        // stage A: bf16 direct 16B copies
#pragma unroll
        for (int p = 0; p < 2; p++) {
            int r   = (t >> 2) + p * 64;
            int seg = (t & 3) * 8;
            uint4 vv = *(const uint4*)&ctx[(size_t)(m0 + r) * HIDDEN + kk + seg];
            *(uint4*)&a_lds[r][seg] = vv;
        }
        // stage B transposed fp32 -> bf16
#pragma unroll
        for (int p = 0; p < 4; p++) {
            int kr = (t >> 5) + p * 8;
            int n4 = (t & 31) * 4;
            const float4 vv = *(const float4*)&w[(size_t)(kk + kr) * HIDDEN + n0 + n4];
            b_lds[n4 + 0][kr] = f2bf(vv.x);
            b_lds[n4 + 1][kr] = f2bf(vv.y);
            b_lds[n4 + 2][kr] = f2bf(vv.z);
            b_lds[n4 + 3][kr] = f2bf(vv.w);
        }
        __syncthreads();

        bf16x8 af[4], bfr[4];
#pragma unroll
        for (int m = 0; m < 4; m++)
            af[m] = *(const bf16x8*)&a_lds[wr * 64 + m * 16 + lr][lg * 8];
#pragma unroll
        for (int n = 0; n < 4; n++)
            bfr[n] = *(const bf16x8*)&b_lds[wc * 64 + n * 16 + lr][lg * 8];
#pragma unroll
        for (int m = 0; m < 4; m++)
#pragma unroll
            for (int n = 0; n < 4; n++)
                acc[m][n] = __builtin_amdgcn_mfma_f32_16x16x32_bf16(af[m], bfr[n], acc[m][n], 0, 0, 0);
    }

#pragma unroll
    for (int m = 0; m < 4; m++) {
#pragma unroll
        for (int n = 0; n < 4; n++) {
#pragma unroll
            for (int r = 0; r < 4; r++) {
                int row = m0 + wr * 64 + m * 16 + lg * 4 + r;
                int col = n0 + wc * 64 + n * 16 + lr;
                out[(size_t)row * HIDDEN + col] = acc[m][n][r] + bias[col];
            }
        }
    }
}

// ---------------------------------------------------------------------------
extern "C" void kernel_launch(void* const* d_in, const int* in_sizes, int n_in,
                              void* d_out, int out_size, void* d_ws, size_t ws_size,
                              hipStream_t stream)
{
    const float* x    = (const float*)d_in[0];
    const float* qkvw = (const float*)d_in[1];
    const float* qkvb = (const float*)d_in[2];
    const float* outw = (const float*)d_in[3];
    const float* outb = (const float*)d_in[4];
    float* out = (float*)d_out;

    const size_t per = (size_t)BATCH * NHEADS * SEQ * HEAD; // 8388608 bf16 elems
    u16* q_ws = (u16*)d_ws;
    u16* k_ws = q_ws + per;
    u16* v_ws = k_ws + per;
    u16* c_ws = v_ws + per;

    qkv_gemm<<<dim3(H3 / 128, BS / 128), 256, 0, stream>>>(x, qkvw, qkvb, q_ws, k_ws, v_ws);
    // 64 (b,h) pairs x 32 q-tiles of 64 rows = 2048 blocks
    attn_kernel<<<dim3(BATCH * NHEADS * (SEQ / 64)), 256, 0, stream>>>(q_ws, k_ws, v_ws, c_ws);
    out_gemm<<<dim3(HIDDEN / 128, BS / 128), 256, 0, stream>>>(c_ws, outw, outb, out);
}

// Round 3
// 549.530 us; speedup vs baseline: 1.2052x; 1.2052x over previous
//
#include <hip/hip_runtime.h>

#define HIDDEN 1024
#define NHEADS 16
#define HEAD   64
#define BATCH  4
#define SEQ    2048
#define BS     (BATCH*SEQ)   // 8192
#define H3     (3*HIDDEN)    // 3072

typedef unsigned short u16;
typedef unsigned int   u32;
typedef __bf16 bf16x8 __attribute__((ext_vector_type(8)));
typedef float  f32x4  __attribute__((ext_vector_type(4)));

__device__ __forceinline__ u16 f2bf(float f) {
    union { float f; u32 u; } v; v.f = f;
    u32 u = v.u;
    u32 r = u + 0x7FFFu + ((u >> 16) & 1u);
    return (u16)(r >> 16);
}

// ---------------------------------------------------------------------------
// GEMM1: qkv = x @ qkv_w + qkv_b  ->  Q (x0.125) [B,H,S,64] / K [B,H,S,64]
//                                     / V^T [B,H,64,S]   (all bf16)
// ---------------------------------------------------------------------------
__global__ __launch_bounds__(256) void qkv_gemm(
    const float* __restrict__ x, const float* __restrict__ w,
    const float* __restrict__ bias,
    u16* __restrict__ q_ws, u16* __restrict__ k_ws, u16* __restrict__ vt_ws)
{
    __shared__ u16 a_lds[128][40];   // [m][k] bf16, +8 pad
    __shared__ u16 b_lds[128][40];   // [n][k] bf16 (transposed), +8 pad

    const int t    = threadIdx.x;
    const int m0   = blockIdx.y * 128;
    const int n0   = blockIdx.x * 128;
    const int lane = t & 63, wv = t >> 6;
    const int lr   = lane & 15, lg = lane >> 4;
    const int wr   = wv >> 1, wc = wv & 1;

    f32x4 acc[4][4];
#pragma unroll
    for (int m = 0; m < 4; m++)
#pragma unroll
        for (int n = 0; n < 4; n++)
#pragma unroll
            for (int r = 0; r < 4; r++) acc[m][n][r] = 0.f;

    for (int kk = 0; kk < HIDDEN; kk += 32) {
        __syncthreads();
        // stage A [128][32] fp32 -> bf16
#pragma unroll
        for (int p = 0; p < 4; p++) {
            int r  = (t >> 3) + p * 32;
            int c4 = (t & 7) * 4;
            const float4 vv = *(const float4*)&x[(size_t)(m0 + r) * HIDDEN + kk + c4];
            ushort4 uu;
            uu.x = f2bf(vv.x); uu.y = f2bf(vv.y); uu.z = f2bf(vv.z); uu.w = f2bf(vv.w);
            *(ushort4*)&a_lds[r][c4] = uu;
        }
        // stage B [32][128] fp32 -> transposed bf16 [128][32]
#pragma unroll
        for (int p = 0; p < 4; p++) {
            int kr = (t >> 5) + p * 8;
            int n4 = (t & 31) * 4;
            const float4 vv = *(const float4*)&w[(size_t)(kk + kr) * H3 + n0 + n4];
            b_lds[n4 + 0][kr] = f2bf(vv.x);
            b_lds[n4 + 1][kr] = f2bf(vv.y);
            b_lds[n4 + 2][kr] = f2bf(vv.z);
            b_lds[n4 + 3][kr] = f2bf(vv.w);
        }
        __syncthreads();

        bf16x8 af[4], bfr[4];
#pragma unroll
        for (int m = 0; m < 4; m++)
            af[m] = *(const bf16x8*)&a_lds[wr * 64 + m * 16 + lr][lg * 8];
#pragma unroll
        for (int n = 0; n < 4; n++)
            bfr[n] = *(const bf16x8*)&b_lds[wc * 64 + n * 16 + lr][lg * 8];
#pragma unroll
        for (int m = 0; m < 4; m++)
#pragma unroll
            for (int n = 0; n < 4; n++)
                acc[m][n] = __builtin_amdgcn_mfma_f32_16x16x32_bf16(af[m], bfr[n], acc[m][n], 0, 0, 0);
    }

    // epilogue: route columns to Q/K/V^T
#pragma unroll
    for (int m = 0; m < 4; m++) {
#pragma unroll
        for (int n = 0; n < 4; n++) {
#pragma unroll
            for (int r = 0; r < 4; r++) {
                int row = m0 + wr * 64 + m * 16 + lg * 4 + r;
                int col = n0 + wc * 64 + n * 16 + lr;
                float val = acc[m][n][r] + bias[col];
                int which = col >> 10;
                int cid   = col & 1023;
                int h = cid >> 6, d = cid & 63;
                int b = row >> 11, s = row & 2047;
                int bh = b * NHEADS + h;
                if (which == 0)
                    q_ws[((size_t)bh * SEQ + s) * HEAD + d] = f2bf(val * 0.125f); // fold 1/sqrt(64)
                else if (which == 1)
                    k_ws[((size_t)bh * SEQ + s) * HEAD + d] = f2bf(val);
                else
                    vt_ws[((size_t)bh * HEAD + d) * SEQ + s] = f2bf(val);        // transposed
            }
        }
    }
}

// ---------------------------------------------------------------------------
// Causal flash attention, double-buffered K/V^T staging, 1 barrier per tile.
// Block = (b*h, 64-row q-tile); 4 waves x 16 q-rows.
// ---------------------------------------------------------------------------
__global__ __launch_bounds__(256) void attn_kernel(
    const u16* __restrict__ q_ws, const u16* __restrict__ k_ws,
    const u16* __restrict__ vt_ws, u16* __restrict__ ctx_ws)
{
    __shared__ u16 k_lds[2][64][72];   // [buf][kcol][d]
    __shared__ u16 vt_lds[2][64][72];  // [buf][d][kcol]
    __shared__ u16 p_lds[4][16][72];   // per-wave P bounce [qrow][kcol]

    const int t  = threadIdx.x;
    const int g  = blockIdx.x;
    // XCD swizzle: all 32 q-tiles of one (b,h) land on one XCD (KV = 512KB,
    // 8 bh per XCD = 4MB = L2). Longest q-tiles first.
    const int bh = ((g >> 8) << 3) | (g & 7);
    const int qt = 31 - ((g >> 3) & 31);

    const int lane = t & 63, wv = t >> 6;
    const int lr   = lane & 15, lg = lane >> 4;
    const int srow = t >> 2;           // 0..63 staging row
    const int sseg = (t & 3) * 16;     // 0/16/32/48 staging col offset

    const u16* kbase = k_ws  + (size_t)bh * SEQ * HEAD;
    const u16* vbase = vt_ws + (size_t)bh * HEAD * SEQ;

    // Q fragments (Q pre-scaled by 1/8)
    const int qr0 = qt * 64 + wv * 16;
    bf16x8 qa[2];
#pragma unroll
    for (int ks = 0; ks < 2; ks++)
        qa[ks] = *(const bf16x8*)&q_ws[((size_t)bh * SEQ + qr0 + lr) * HEAD + ks * 32 + lg * 8];

    // prologue: stage tile 0 into buffer 0
    {
        const u16* kp = &kbase[(size_t)srow * HEAD + sseg];
        const u16* vp = &vbase[(size_t)srow * SEQ + sseg];
        uint4 a0 = *(const uint4*)kp;
        uint4 a1 = *(const uint4*)(kp + 8);
        uint4 b0 = *(const uint4*)vp;
        uint4 b1 = *(const uint4*)(vp + 8);
        *(uint4*)&k_lds[0][srow][sseg]      = a0;
        *(uint4*)&k_lds[0][srow][sseg + 8]  = a1;
        *(uint4*)&vt_lds[0][srow][sseg]     = b0;
        *(uint4*)&vt_lds[0][srow][sseg + 8] = b1;
    }
    __syncthreads();

    f32x4 acc_o[4];
#pragma unroll
    for (int df = 0; df < 4; df++)
#pragma unroll
        for (int r = 0; r < 4; r++) acc_o[df][r] = 0.f;
    float m_run[4], l_run[4];
#pragma unroll
    for (int r = 0; r < 4; r++) { m_run[r] = -3e38f; l_run[r] = 0.f; }

    int cur = 0;
    for (int kt = 0; kt <= qt; kt++) {
        const bool pf = (kt < qt);
        uint4 kn0, kn1, vn0, vn1;
        if (pf) {  // issue next tile's loads early; latency hides under compute
            const u16* kp = &kbase[(size_t)((kt + 1) * 64 + srow) * HEAD + sseg];
            const u16* vp = &vbase[(size_t)srow * SEQ + (kt + 1) * 64 + sseg];
            kn0 = *(const uint4*)kp;
            kn1 = *(const uint4*)(kp + 8);
            vn0 = *(const uint4*)vp;
            vn1 = *(const uint4*)(vp + 8);
        }

        // QK^T : S[16 q][64 k]
        f32x4 s_acc[4];
#pragma unroll
        for (int nf = 0; nf < 4; nf++) {
#pragma unroll
            for (int r = 0; r < 4; r++) s_acc[nf][r] = 0.f;
#pragma unroll
            for (int ks = 0; ks < 2; ks++) {
                bf16x8 kb = *(const bf16x8*)&k_lds[cur][nf * 16 + lr][ks * 32 + lg * 8];
                s_acc[nf] = __builtin_amdgcn_mfma_f32_16x16x32_bf16(qa[ks], kb, s_acc[nf], 0, 0, 0);
            }
        }

        if (kt == qt) {  // strict causal mask on diagonal tile
#pragma unroll
            for (int nf = 0; nf < 4; nf++)
#pragma unroll
                for (int r = 0; r < 4; r++) {
                    int gq = wv * 16 + lg * 4 + r;
                    int gk = nf * 16 + lr;
                    if (gk > gq) s_acc[nf][r] = -1e9f;
                }
        }

        // online softmax (reduce over 16-lane group = k columns)
        float p[4][4];
#pragma unroll
        for (int r = 0; r < 4; r++) {
            float mx = fmaxf(fmaxf(s_acc[0][r], s_acc[1][r]), fmaxf(s_acc[2][r], s_acc[3][r]));
#pragma unroll
            for (int off = 8; off >= 1; off >>= 1)
                mx = fmaxf(mx, __shfl_xor(mx, off));
            float m_new = fmaxf(m_run[r], mx);
            float sc = __expf(m_run[r] - m_new);
            float rs = 0.f;
#pragma unroll
            for (int nf = 0; nf < 4; nf++) {
                p[nf][r] = __expf(s_acc[nf][r] - m_new);
                rs += p[nf][r];
            }
#pragma unroll
            for (int off = 8; off >= 1; off >>= 1)
                rs += __shfl_xor(rs, off);
            l_run[r] = l_run[r] * sc + rs;
            m_run[r] = m_new;
#pragma unroll
            for (int df = 0; df < 4; df++) acc_o[df][r] *= sc;
        }

        // P bounce through per-wave LDS (wave-local: no block barrier needed,
        // compiler inserts lgkmcnt wait for the read-after-write)
#pragma unroll
        for (int nf = 0; nf < 4; nf++)
#pragma unroll
            for (int r = 0; r < 4; r++)
                p_lds[wv][lg * 4 + r][nf * 16 + lr] = f2bf(p[nf][r]);

        bf16x8 pa[2];
#pragma unroll
        for (int ks = 0; ks < 2; ks++)
            pa[ks] = *(const bf16x8*)&p_lds[wv][lr][ks * 32 + lg * 8];

        // PV: O[16 q][64 d]
#pragma unroll
        for (int df = 0; df < 4; df++) {
#pragma unroll
            for (int ks = 0; ks < 2; ks++) {
                bf16x8 vb = *(const bf16x8*)&vt_lds[cur][df * 16 + lr][ks * 32 + lg * 8];
                acc_o[df] = __builtin_amdgcn_mfma_f32_16x16x32_bf16(pa[ks], vb, acc_o[df], 0, 0, 0);
            }
        }

        if (pf) {
            const int nxt = cur ^ 1;
            // nxt was last read before the previous barrier -> safe to fill now
            *(uint4*)&k_lds[nxt][srow][sseg]      = kn0;
            *(uint4*)&k_lds[nxt][srow][sseg + 8]  = kn1;
            *(uint4*)&vt_lds[nxt][srow][sseg]     = vn0;
            *(uint4*)&vt_lds[nxt][srow][sseg + 8] = vn1;
            __syncthreads();   // single barrier per tile
            cur = nxt;
        }
    }

    // epilogue: ctx [B,S, h*64+d] bf16
    const int b = bh >> 4, h = bh & 15;
#pragma unroll
    for (int r = 0; r < 4; r++) {
        float inv = 1.f / l_run[r];
        int s = qt * 64 + wv * 16 + lg * 4 + r;
#pragma unroll
        for (int df = 0; df < 4; df++) {
            int d = df * 16 + lr;
            ctx_ws[((size_t)(b * SEQ + s)) * HIDDEN + h * HEAD + d] = f2bf(acc_o[df][r] * inv);
        }
    }
}

// ---------------------------------------------------------------------------
// GEMM2: out = ctx(bf16) @ out_w + out_b   (fp32 out)
// ---------------------------------------------------------------------------
__global__ __launch_bounds__(256) void out_gemm(
    const u16* __restrict__ ctx, const float* __restrict__ w,
    const float* __restrict__ bias, float* __restrict__ out)
{
    __shared__ u16 a_lds[128][40];
    __shared__ u16 b_lds[128][40];

    const int t    = threadIdx.x;
    const int m0   = blockIdx.y * 128;
    const int n0   = blockIdx.x * 128;
    const int lane = t & 63, wv = t >> 6;
    const int lr   = lane & 15, lg = lane >> 4;
    const int wr   = wv >> 1, wc = wv & 1;

    f32x4 acc[4][4];
#pragma unroll
    for (int m = 0; m < 4; m++)
#pragma unroll
        for (int n = 0; n < 4; n++)
#pragma unroll
            for (int r = 0; r < 4; r++) acc[m][n][r] = 0.f;

    for (int kk = 0; kk < HIDDEN; kk += 32) {
        __syncthreads();
        // stage A: bf16 direct 16B copies
#pragma unroll
        for (int p = 0; p < 2; p++) {
            int r   = (t >> 2) + p * 64;
            int seg = (t & 3) * 8;
            uint4 vv = *(const uint4*)&ctx[(size_t)(m0 + r) * HIDDEN + kk + seg];
            *(uint4*)&a_lds[r][seg] = vv;
        }
        // stage B transposed fp32 -> bf16
#pragma unroll
        for (int p = 0; p < 4; p++) {
            int kr = (t >> 5) + p * 8;
            int n4 = (t & 31) * 4;
            const float4 vv = *(const float4*)&w[(size_t)(kk + kr) * HIDDEN + n0 + n4];
            b_lds[n4 + 0][kr] = f2bf(vv.x);
            b_lds[n4 + 1][kr] = f2bf(vv.y);
            b_lds[n4 + 2][kr] = f2bf(vv.z);
            b_lds[n4 + 3][kr] = f2bf(vv.w);
        }
        __syncthreads();

        bf16x8 af[4], bfr[4];
#pragma unroll
        for (int m = 0; m < 4; m++)
            af[m] = *(const bf16x8*)&a_lds[wr * 64 + m * 16 + lr][lg * 8];
#pragma unroll
        for (int n = 0; n < 4; n++)
            bfr[n] = *(const bf16x8*)&b_lds[wc * 64 + n * 16 + lr][lg * 8];
#pragma unroll
        for (int m = 0; m < 4; m++)
#pragma unroll
            for (int n = 0; n < 4; n++)
                acc[m][n] = __builtin_amdgcn_mfma_f32_16x16x32_bf16(af[m], bfr[n], acc[m][n], 0, 0, 0);
    }

#pragma unroll
    for (int m = 0; m < 4; m++) {
#pragma unroll
        for (int n = 0; n < 4; n++) {
#pragma unroll
            for (int r = 0; r < 4; r++) {
                int row = m0 + wr * 64 + m * 16 + lg * 4 + r;
                int col = n0 + wc * 64 + n * 16 + lr;
                out[(size_t)row * HIDDEN + col] = acc[m][n][r] + bias[col];
            }
        }
    }
}

// ---------------------------------------------------------------------------
extern "C" void kernel_launch(void* const* d_in, const int* in_sizes, int n_in,
                              void* d_out, int out_size, void* d_ws, size_t ws_size,
                              hipStream_t stream)
{
    const float* x    = (const float*)d_in[0];
    const float* qkvw = (const float*)d_in[1];
    const float* qkvb = (const float*)d_in[2];
    const float* outw = (const float*)d_in[3];
    const float* outb = (const float*)d_in[4];
    float* out = (float*)d_out;

    const size_t per = (size_t)BATCH * NHEADS * SEQ * HEAD; // 8388608 bf16 elems
    u16* q_ws  = (u16*)d_ws;
    u16* k_ws  = q_ws + per;
    u16* vt_ws = k_ws + per;
    u16* c_ws  = vt_ws + per;

    qkv_gemm<<<dim3(H3 / 128, BS / 128), 256, 0, stream>>>(x, qkvw, qkvb, q_ws, k_ws, vt_ws);
    attn_kernel<<<dim3(BATCH * NHEADS * (SEQ / 64)), 256, 0, stream>>>(q_ws, k_ws, vt_ws, c_ws);
    out_gemm<<<dim3(HIDDEN / 128, BS / 128), 256, 0, stream>>>(c_ws, outw, outb, out);
}

// Round 5
// 373.505 us; speedup vs baseline: 1.7732x; 1.4713x over previous
//
#include <hip/hip_runtime.h>

#define HIDDEN 1024
#define NHEADS 16
#define HEAD   64
#define BATCH  4
#define SEQ    2048
#define BS     (BATCH*SEQ)   // 8192
#define H3     (3*HIDDEN)    // 3072

typedef unsigned short u16;
typedef unsigned int   u32;
typedef __bf16 bf16x8 __attribute__((ext_vector_type(8)));
typedef float  f32x4  __attribute__((ext_vector_type(4)));

__device__ __forceinline__ u16 f2bf(float f) {
    union { float f; u32 u; } v; v.f = f;
    u32 u = v.u;
    u32 r = u + 0x7FFFu + ((u >> 16) & 1u);
    return (u16)(r >> 16);
}

// async global->LDS 16B: HW writes lane l's data to readfirstlane(lds)+l*16,
// so pass per-lane lds = base + lane*16 (linear layout, no swizzle).
__device__ __forceinline__ void gload_lds16(const u16* g, u16* l) {
    __builtin_amdgcn_global_load_lds(
        (const __attribute__((address_space(1))) void*)g,
        (__attribute__((address_space(3))) void*)l, 16, 0, 0);
}

// ---------------------------------------------------------------------------
// conv_x: fp32 -> bf16, same layout. 8 elems/thread.
// ---------------------------------------------------------------------------
__global__ __launch_bounds__(256) void conv_x(
    const float* __restrict__ in, u16* __restrict__ out)
{
    const size_t i = ((size_t)blockIdx.x * 256 + threadIdx.x) * 8;
    float4 v0 = *(const float4*)&in[i];
    float4 v1 = *(const float4*)&in[i + 4];
    u16 u[8];
    u[0]=f2bf(v0.x); u[1]=f2bf(v0.y); u[2]=f2bf(v0.z); u[3]=f2bf(v0.w);
    u[4]=f2bf(v1.x); u[5]=f2bf(v1.y); u[6]=f2bf(v1.z); u[7]=f2bf(v1.w);
    *(uint4*)&out[i] = *(uint4*)u;
}

// ---------------------------------------------------------------------------
// conv_wt: w [1024][N] fp32 -> wt [N][1024] bf16 (transpose+convert)
// 64x64 LDS tiles. grid = (N/64, 1024/64)
// ---------------------------------------------------------------------------
__global__ __launch_bounds__(256) void conv_wt(
    const float* __restrict__ w, u16* __restrict__ wt, int N)
{
    __shared__ float tile[64][65];
    const int t  = threadIdx.x;
    const int n0 = blockIdx.x * 64;
    const int k0 = blockIdx.y * 64;
#pragma unroll
    for (int i = 0; i < 4; i++) {
        int kr = i * 16 + (t >> 4);
        int c4 = (t & 15) * 4;
        float4 v = *(const float4*)&w[(size_t)(k0 + kr) * N + n0 + c4];
        tile[kr][c4+0] = v.x; tile[kr][c4+1] = v.y;
        tile[kr][c4+2] = v.z; tile[kr][c4+3] = v.w;
    }
    __syncthreads();
#pragma unroll
    for (int i = 0; i < 4; i++) {
        int nr = i * 16 + (t >> 4);
        int k4 = (t & 15) * 4;
        ushort4 uu;
        uu.x = f2bf(tile[k4+0][nr]); uu.y = f2bf(tile[k4+1][nr]);
        uu.z = f2bf(tile[k4+2][nr]); uu.w = f2bf(tile[k4+3][nr]);
        *(ushort4*)&wt[(size_t)(n0 + nr) * 1024 + k0 + k4] = uu;
    }
}

// ---------------------------------------------------------------------------
// GEMM1 (m97 structure): C = xb[8192][1024] @ wqkvt[3072][1024]^T  + bias
// epilogue scatters to Q(x0.125)[B,H,S,64] / K[B,H,S,64] / V^T[B,H,64,S]
// ---------------------------------------------------------------------------
__global__ __launch_bounds__(256) void qkv_gemm(
    const u16* __restrict__ A, const u16* __restrict__ Bt,
    const float* __restrict__ bias,
    u16* __restrict__ q_ws, u16* __restrict__ k_ws, u16* __restrict__ vt_ws)
{
    __shared__ u16 a_lds[128 * 64];
    __shared__ u16 b_lds[128 * 64];

    // bijective XCD-chunk swizzle: nwg = 64*24 = 1536, 192 per XCD
    const int swz    = (blockIdx.x & 7) * 192 + (blockIdx.x >> 3);
    const int m0     = (swz / 24) * 128;
    const int n0     = (swz % 24) * 128;

    const int t    = threadIdx.x;
    const int lane = t & 63, wv = t >> 6;
    const int lr   = lane & 15, lg = lane >> 4;
    const int wr   = wv >> 1, wc = wv & 1;
    const int srow = wv * 32 + (lane >> 3);   // staging row base (i*8 added)
    const int sseg = (lane & 7) * 8;          // staging col

    f32x4 acc[4][4];
#pragma unroll
    for (int m = 0; m < 4; m++)
#pragma unroll
        for (int n = 0; n < 4; n++)
#pragma unroll
            for (int r = 0; r < 4; r++) acc[m][n][r] = 0.f;

    for (int kt = 0; kt < 16; kt++) {
        const int kk = kt * 64;
        __syncthreads();
#pragma unroll
        for (int i = 0; i < 4; i++) {
            int row = srow + i * 8;
            gload_lds16(&A [(size_t)(m0 + row) * 1024 + kk + sseg], &a_lds[row * 64 + sseg]);
            gload_lds16(&Bt[(size_t)(n0 + row) * 1024 + kk + sseg], &b_lds[row * 64 + sseg]);
        }
        __syncthreads();

        bf16x8 af[2][4], bf[2][4];
#pragma unroll
        for (int ks = 0; ks < 2; ks++) {
#pragma unroll
            for (int m = 0; m < 4; m++)
                af[ks][m] = *(const bf16x8*)&a_lds[(wr * 64 + m * 16 + lr) * 64 + ks * 32 + lg * 8];
#pragma unroll
            for (int n = 0; n < 4; n++)
                bf[ks][n] = *(const bf16x8*)&b_lds[(wc * 64 + n * 16 + lr) * 64 + ks * 32 + lg * 8];
        }
#pragma unroll
        for (int ks = 0; ks < 2; ks++)
#pragma unroll
            for (int m = 0; m < 4; m++)
#pragma unroll
                for (int n = 0; n < 4; n++)
                    acc[m][n] = __builtin_amdgcn_mfma_f32_16x16x32_bf16(af[ks][m], bf[ks][n], acc[m][n], 0, 0, 0);
    }

    // epilogue: route to Q/K/V^T
#pragma unroll
    for (int m = 0; m < 4; m++) {
#pragma unroll
        for (int n = 0; n < 4; n++) {
#pragma unroll
            for (int r = 0; r < 4; r++) {
                int row = m0 + wr * 64 + m * 16 + lg * 4 + r;
                int col = n0 + wc * 64 + n * 16 + lr;
                float val = acc[m][n][r] + bias[col];
                int which = col >> 10;
                int cid   = col & 1023;
                int h = cid >> 6, d = cid & 63;
                int b = row >> 11, s = row & 2047;
                int bh = b * NHEADS + h;
                if (which == 0)
                    q_ws[((size_t)bh * SEQ + s) * HEAD + d] = f2bf(val * 0.125f);
                else if (which == 1)
                    k_ws[((size_t)bh * SEQ + s) * HEAD + d] = f2bf(val);
                else
                    vt_ws[((size_t)bh * HEAD + d) * SEQ + s] = f2bf(val);
            }
        }
    }
}

// ---------------------------------------------------------------------------
// GEMM2 (m97 structure): out = ctx[8192][1024] @ wot[1024][1024]^T + out_b (fp32)
// ---------------------------------------------------------------------------
__global__ __launch_bounds__(256) void out_gemm(
    const u16* __restrict__ A, const u16* __restrict__ Bt,
    const float* __restrict__ bias, float* __restrict__ out)
{
    __shared__ u16 a_lds[128 * 64];
    __shared__ u16 b_lds[128 * 64];

    // nwg = 64*8 = 512, 64 per XCD
    const int swz = (blockIdx.x & 7) * 64 + (blockIdx.x >> 3);
    const int m0  = (swz >> 3) * 128;
    const int n0  = (swz & 7) * 128;

    const int t    = threadIdx.x;
    const int lane = t & 63, wv = t >> 6;
    const int lr   = lane & 15, lg = lane >> 4;
    const int wr   = wv >> 1, wc = wv & 1;
    const int srow = wv * 32 + (lane >> 3);
    const int sseg = (lane & 7) * 8;

    f32x4 acc[4][4];
#pragma unroll
    for (int m = 0; m < 4; m++)
#pragma unroll
        for (int n = 0; n < 4; n++)
#pragma unroll
            for (int r = 0; r < 4; r++) acc[m][n][r] = 0.f;

    for (int kt = 0; kt < 16; kt++) {
        const int kk = kt * 64;
        __syncthreads();
#pragma unroll
        for (int i = 0; i < 4; i++) {
            int row = srow + i * 8;
            gload_lds16(&A [(size_t)(m0 + row) * 1024 + kk + sseg], &a_lds[row * 64 + sseg]);
            gload_lds16(&Bt[(size_t)(n0 + row) * 1024 + kk + sseg], &b_lds[row * 64 + sseg]);
        }
        __syncthreads();

        bf16x8 af[2][4], bf[2][4];
#pragma unroll
        for (int ks = 0; ks < 2; ks++) {
#pragma unroll
            for (int m = 0; m < 4; m++)
                af[ks][m] = *(const bf16x8*)&a_lds[(wr * 64 + m * 16 + lr) * 64 + ks * 32 + lg * 8];
#pragma unroll
            for (int n = 0; n < 4; n++)
                bf[ks][n] = *(const bf16x8*)&b_lds[(wc * 64 + n * 16 + lr) * 64 + ks * 32 + lg * 8];
        }
#pragma unroll
        for (int ks = 0; ks < 2; ks++)
#pragma unroll
            for (int m = 0; m < 4; m++)
#pragma unroll
                for (int n = 0; n < 4; n++)
                    acc[m][n] = __builtin_amdgcn_mfma_f32_16x16x32_bf16(af[ks][m], bf[ks][n], acc[m][n], 0, 0, 0);
    }

#pragma unroll
    for (int m = 0; m < 4; m++) {
#pragma unroll
        for (int n = 0; n < 4; n++) {
#pragma unroll
            for (int r = 0; r < 4; r++) {
                int row = m0 + wr * 64 + m * 16 + lg * 4 + r;
                int col = n0 + wc * 64 + n * 16 + lr;
                out[(size_t)row * HIDDEN + col] = acc[m][n][r] + bias[col];
            }
        }
    }
}

// ---------------------------------------------------------------------------
// Causal flash attention (unchanged from round 3)
// ---------------------------------------------------------------------------
__global__ __launch_bounds__(256) void attn_kernel(
    const u16* __restrict__ q_ws, const u16* __restrict__ k_ws,
    const u16* __restrict__ vt_ws, u16* __restrict__ ctx_ws)
{
    __shared__ u16 k_lds[2][64][72];
    __shared__ u16 vt_lds[2][64][72];
    __shared__ u16 p_lds[4][16][72];

    const int t  = threadIdx.x;
    const int g  = blockIdx.x;
    const int bh = ((g >> 8) << 3) | (g & 7);
    const int qt = 31 - ((g >> 3) & 31);

    const int lane = t & 63, wv = t >> 6;
    const int lr   = lane & 15, lg = lane >> 4;
    const int srow = t >> 2;
    const int sseg = (t & 3) * 16;

    const u16* kbase = k_ws  + (size_t)bh * SEQ * HEAD;
    const u16* vbase = vt_ws + (size_t)bh * HEAD * SEQ;

    const int qr0 = qt * 64 + wv * 16;
    bf16x8 qa[2];
#pragma unroll
    for (int ks = 0; ks < 2; ks++)
        qa[ks] = *(const bf16x8*)&q_ws[((size_t)bh * SEQ + qr0 + lr) * HEAD + ks * 32 + lg * 8];

    {
        const u16* kp = &kbase[(size_t)srow * HEAD + sseg];
        const u16* vp = &vbase[(size_t)srow * SEQ + sseg];
        uint4 a0 = *(const uint4*)kp;
        uint4 a1 = *(const uint4*)(kp + 8);
        uint4 b0 = *(const uint4*)vp;
        uint4 b1 = *(const uint4*)(vp + 8);
        *(uint4*)&k_lds[0][srow][sseg]      = a0;
        *(uint4*)&k_lds[0][srow][sseg + 8]  = a1;
        *(uint4*)&vt_lds[0][srow][sseg]     = b0;
        *(uint4*)&vt_lds[0][srow][sseg + 8] = b1;
    }
    __syncthreads();

    f32x4 acc_o[4];
#pragma unroll
    for (int df = 0; df < 4; df++)
#pragma unroll
        for (int r = 0; r < 4; r++) acc_o[df][r] = 0.f;
    float m_run[4], l_run[4];
#pragma unroll
    for (int r = 0; r < 4; r++) { m_run[r] = -3e38f; l_run[r] = 0.f; }

    int cur = 0;
    for (int kt = 0; kt <= qt; kt++) {
        const bool pf = (kt < qt);
        uint4 kn0, kn1, vn0, vn1;
        if (pf) {
            const u16* kp = &kbase[(size_t)((kt + 1) * 64 + srow) * HEAD + sseg];
            const u16* vp = &vbase[(size_t)srow * SEQ + (kt + 1) * 64 + sseg];
            kn0 = *(const uint4*)kp;
            kn1 = *(const uint4*)(kp + 8);
            vn0 = *(const uint4*)vp;
            vn1 = *(const uint4*)(vp + 8);
        }

        f32x4 s_acc[4];
#pragma unroll
        for (int nf = 0; nf < 4; nf++) {
#pragma unroll
            for (int r = 0; r < 4; r++) s_acc[nf][r] = 0.f;
#pragma unroll
            for (int ks = 0; ks < 2; ks++) {
                bf16x8 kb = *(const bf16x8*)&k_lds[cur][nf * 16 + lr][ks * 32 + lg * 8];
                s_acc[nf] = __builtin_amdgcn_mfma_f32_16x16x32_bf16(qa[ks], kb, s_acc[nf], 0, 0, 0);
            }
        }

        if (kt == qt) {
#pragma unroll
            for (int nf = 0; nf < 4; nf++)
#pragma unroll
                for (int r = 0; r < 4; r++) {
                    int gq = wv * 16 + lg * 4 + r;
                    int gk = nf * 16 + lr;
                    if (gk > gq) s_acc[nf][r] = -1e9f;
                }
        }

        float p[4][4];
#pragma unroll
        for (int r = 0; r < 4; r++) {
            float mx = fmaxf(fmaxf(s_acc[0][r], s_acc[1][r]), fmaxf(s_acc[2][r], s_acc[3][r]));
#pragma unroll
            for (int off = 8; off >= 1; off >>= 1)
                mx = fmaxf(mx, __shfl_xor(mx, off));
            float m_new = fmaxf(m_run[r], mx);
            float sc = __expf(m_run[r] - m_new);
            float rs = 0.f;
#pragma unroll
            for (int nf = 0; nf < 4; nf++) {
                p[nf][r] = __expf(s_acc[nf][r] - m_new);
                rs += p[nf][r];
            }
#pragma unroll
            for (int off = 8; off >= 1; off >>= 1)
                rs += __shfl_xor(rs, off);
            l_run[r] = l_run[r] * sc + rs;
            m_run[r] = m_new;
#pragma unroll
            for (int df = 0; df < 4; df++) acc_o[df][r] *= sc;
        }

#pragma unroll
        for (int nf = 0; nf < 4; nf++)
#pragma unroll
            for (int r = 0; r < 4; r++)
                p_lds[wv][lg * 4 + r][nf * 16 + lr] = f2bf(p[nf][r]);

        bf16x8 pa[2];
#pragma unroll
        for (int ks = 0; ks < 2; ks++)
            pa[ks] = *(const bf16x8*)&p_lds[wv][lr][ks * 32 + lg * 8];

#pragma unroll
        for (int df = 0; df < 4; df++) {
#pragma unroll
            for (int ks = 0; ks < 2; ks++) {
                bf16x8 vb = *(const bf16x8*)&vt_lds[cur][df * 16 + lr][ks * 32 + lg * 8];
                acc_o[df] = __builtin_amdgcn_mfma_f32_16x16x32_bf16(pa[ks], vb, acc_o[df], 0, 0, 0);
            }
        }

        if (pf) {
            const int nxt = cur ^ 1;
            *(uint4*)&k_lds[nxt][srow][sseg]      = kn0;
            *(uint4*)&k_lds[nxt][srow][sseg + 8]  = kn1;
            *(uint4*)&vt_lds[nxt][srow][sseg]     = vn0;
            *(uint4*)&vt_lds[nxt][srow][sseg + 8] = vn1;
            __syncthreads();
            cur = nxt;
        }
    }

    const int b = bh >> 4, h = bh & 15;
#pragma unroll
    for (int r = 0; r < 4; r++) {
        float inv = 1.f / l_run[r];
        int s = qt * 64 + wv * 16 + lg * 4 + r;
#pragma unroll
        for (int df = 0; df < 4; df++) {
            int d = df * 16 + lr;
            ctx_ws[((size_t)(b * SEQ + s)) * HIDDEN + h * HEAD + d] = f2bf(acc_o[df][r] * inv);
        }
    }
}

// ---------------------------------------------------------------------------
extern "C" void kernel_launch(void* const* d_in, const int* in_sizes, int n_in,
                              void* d_out, int out_size, void* d_ws, size_t ws_size,
                              hipStream_t stream)
{
    const float* x    = (const float*)d_in[0];
    const float* qkvw = (const float*)d_in[1];
    const float* qkvb = (const float*)d_in[2];
    const float* outw = (const float*)d_in[3];
    const float* outb = (const float*)d_in[4];
    float* out = (float*)d_out;

    const size_t per = (size_t)BATCH * NHEADS * SEQ * HEAD; // 8388608 elems
    u16* q_ws   = (u16*)d_ws;
    u16* k_ws   = q_ws + per;
    u16* vt_ws  = k_ws + per;
    u16* c_ws   = vt_ws + per;          // ctx; also aliases nothing live
    u16* xb     = c_ws + per;           // x in bf16 (dead after qkv_gemm)
    u16* wqkvt  = xb + per;             // [3072][1024] bf16
    u16* wot    = wqkvt + (size_t)H3 * HIDDEN; // [1024][1024] bf16

    conv_x <<<dim3((BS * HIDDEN) / (256 * 8)), 256, 0, stream>>>(x, xb);
    conv_wt<<<dim3(H3 / 64, HIDDEN / 64), 256, 0, stream>>>(qkvw, wqkvt, H3);
    conv_wt<<<dim3(HIDDEN / 64, HIDDEN / 64), 256, 0, stream>>>(outw, wot, HIDDEN);

    qkv_gemm<<<dim3(64 * 24), 256, 0, stream>>>(xb, wqkvt, qkvb, q_ws, k_ws, vt_ws);
    attn_kernel<<<dim3(BATCH * NHEADS * (SEQ / 64)), 256, 0, stream>>>(q_ws, k_ws, vt_ws, c_ws);
    out_gemm<<<dim3(64 * 8), 256, 0, stream>>>(c_ws, wot, outb, out);
}

// Round 9
// 351.015 us; speedup vs baseline: 1.8868x; 1.0641x over previous
//
#include <hip/hip_runtime.h>

#define HIDDEN 1024
#define NHEADS 16
#define HEAD   64
#define BATCH  4
#define SEQ    2048
#define BS     (BATCH*SEQ)   // 8192
#define H3     (3*HIDDEN)    // 3072

typedef unsigned short u16;
typedef unsigned int   u32;
typedef __bf16 bf16x8 __attribute__((ext_vector_type(8)));
typedef float  f32x4  __attribute__((ext_vector_type(4)));

__device__ __forceinline__ u16 f2bf(float f) {
    union { float f; u32 u; } v; v.f = f;
    u32 u = v.u;
    u32 r = u + 0x7FFFu + ((u >> 16) & 1u);
    return (u16)(r >> 16);
}

// native cast -> compiler can emit v_cvt_pk_bf16_f32 (RNE)
__device__ __forceinline__ u16 f2bf_n(float f) {
    __bf16 h = (__bf16)f;
    union { __bf16 h; u16 u; } v; v.h = h;
    return v.u;
}

// async global->LDS 16B: HW writes lane l's data to readfirstlane(lds)+l*16,
// so pass per-lane lds = base + lane*16 (linear layout, no swizzle).
__device__ __forceinline__ void gload_lds16(const u16* g, u16* l) {
    __builtin_amdgcn_global_load_lds(
        (const __attribute__((address_space(1))) void*)g,
        (__attribute__((address_space(3))) void*)l, 16, 0, 0);
}

// ---------------------------------------------------------------------------
// conv_x: fp32 -> bf16, same layout. 8 elems/thread.
// ---------------------------------------------------------------------------
__global__ __launch_bounds__(256) void conv_x(
    const float* __restrict__ in, u16* __restrict__ out)
{
    const size_t i = ((size_t)blockIdx.x * 256 + threadIdx.x) * 8;
    float4 v0 = *(const float4*)&in[i];
    float4 v1 = *(const float4*)&in[i + 4];
    u16 u[8];
    u[0]=f2bf(v0.x); u[1]=f2bf(v0.y); u[2]=f2bf(v0.z); u[3]=f2bf(v0.w);
    u[4]=f2bf(v1.x); u[5]=f2bf(v1.y); u[6]=f2bf(v1.z); u[7]=f2bf(v1.w);
    *(uint4*)&out[i] = *(uint4*)u;
}

// ---------------------------------------------------------------------------
// conv_wt: w [1024][N] fp32 -> wt [N][1024] bf16 (transpose+convert)
// ---------------------------------------------------------------------------
__global__ __launch_bounds__(256) void conv_wt(
    const float* __restrict__ w, u16* __restrict__ wt, int N)
{
    __shared__ float tile[64][65];
    const int t  = threadIdx.x;
    const int n0 = blockIdx.x * 64;
    const int k0 = blockIdx.y * 64;
#pragma unroll
    for (int i = 0; i < 4; i++) {
        int kr = i * 16 + (t >> 4);
        int c4 = (t & 15) * 4;
        float4 v = *(const float4*)&w[(size_t)(k0 + kr) * N + n0 + c4];
        tile[kr][c4+0] = v.x; tile[kr][c4+1] = v.y;
        tile[kr][c4+2] = v.z; tile[kr][c4+3] = v.w;
    }
    __syncthreads();
#pragma unroll
    for (int i = 0; i < 4; i++) {
        int nr = i * 16 + (t >> 4);
        int k4 = (t & 15) * 4;
        ushort4 uu;
        uu.x = f2bf(tile[k4+0][nr]); uu.y = f2bf(tile[k4+1][nr]);
        uu.z = f2bf(tile[k4+2][nr]); uu.w = f2bf(tile[k4+3][nr]);
        *(ushort4*)&wt[(size_t)(n0 + nr) * 1024 + k0 + k4] = uu;
    }
}

// ---------------------------------------------------------------------------
// GEMM1 (m97 structure): C = xb[8192][1024] @ wqkvt[3072][1024]^T  + bias
// ---------------------------------------------------------------------------
__global__ __launch_bounds__(256) void qkv_gemm(
    const u16* __restrict__ A, const u16* __restrict__ Bt,
    const float* __restrict__ bias,
    u16* __restrict__ q_ws, u16* __restrict__ k_ws, u16* __restrict__ vt_ws)
{
    __shared__ u16 a_lds[128 * 64];
    __shared__ u16 b_lds[128 * 64];

    const int swz    = (blockIdx.x & 7) * 192 + (blockIdx.x >> 3);
    const int m0     = (swz / 24) * 128;
    const int n0     = (swz % 24) * 128;

    const int t    = threadIdx.x;
    const int lane = t & 63, wv = t >> 6;
    const int lr   = lane & 15, lg = lane >> 4;
    const int wr   = wv >> 1, wc = wv & 1;
    const int srow = wv * 32 + (lane >> 3);
    const int sseg = (lane & 7) * 8;

    f32x4 acc[4][4];
#pragma unroll
    for (int m = 0; m < 4; m++)
#pragma unroll
        for (int n = 0; n < 4; n++)
#pragma unroll
            for (int r = 0; r < 4; r++) acc[m][n][r] = 0.f;

    for (int kt = 0; kt < 16; kt++) {
        const int kk = kt * 64;
        __syncthreads();
#pragma unroll
        for (int i = 0; i < 4; i++) {
            int row = srow + i * 8;
            gload_lds16(&A [(size_t)(m0 + row) * 1024 + kk + sseg], &a_lds[row * 64 + sseg]);
            gload_lds16(&Bt[(size_t)(n0 + row) * 1024 + kk + sseg], &b_lds[row * 64 + sseg]);
        }
        __syncthreads();

        bf16x8 af[2][4], bf[2][4];
#pragma unroll
        for (int ks = 0; ks < 2; ks++) {
#pragma unroll
            for (int m = 0; m < 4; m++)
                af[ks][m] = *(const bf16x8*)&a_lds[(wr * 64 + m * 16 + lr) * 64 + ks * 32 + lg * 8];
#pragma unroll
            for (int n = 0; n < 4; n++)
                bf[ks][n] = *(const bf16x8*)&b_lds[(wc * 64 + n * 16 + lr) * 64 + ks * 32 + lg * 8];
        }
#pragma unroll
        for (int ks = 0; ks < 2; ks++)
#pragma unroll
            for (int m = 0; m < 4; m++)
#pragma unroll
                for (int n = 0; n < 4; n++)
                    acc[m][n] = __builtin_amdgcn_mfma_f32_16x16x32_bf16(af[ks][m], bf[ks][n], acc[m][n], 0, 0, 0);
    }

#pragma unroll
    for (int m = 0; m < 4; m++) {
#pragma unroll
        for (int n = 0; n < 4; n++) {
#pragma unroll
            for (int r = 0; r < 4; r++) {
                int row = m0 + wr * 64 + m * 16 + lg * 4 + r;
                int col = n0 + wc * 64 + n * 16 + lr;
                float val = acc[m][n][r] + bias[col];
                int which = col >> 10;
                int cid   = col & 1023;
                int h = cid >> 6, d = cid & 63;
                int b = row >> 11, s = row & 2047;
                int bh = b * NHEADS + h;
                if (which == 0)
                    q_ws[((size_t)bh * SEQ + s) * HEAD + d] = f2bf(val * 0.125f);
                else if (which == 1)
                    k_ws[((size_t)bh * SEQ + s) * HEAD + d] = f2bf(val);
                else
                    vt_ws[((size_t)bh * HEAD + d) * SEQ + s] = f2bf(val);
            }
        }
    }
}

// ---------------------------------------------------------------------------
// GEMM2 (m97 structure): out = ctx @ wot^T + out_b (fp32)
// ---------------------------------------------------------------------------
__global__ __launch_bounds__(256) void out_gemm(
    const u16* __restrict__ A, const u16* __restrict__ Bt,
    const float* __restrict__ bias, float* __restrict__ out)
{
    __shared__ u16 a_lds[128 * 64];
    __shared__ u16 b_lds[128 * 64];

    const int swz = (blockIdx.x & 7) * 64 + (blockIdx.x >> 3);
    const int m0  = (swz >> 3) * 128;
    const int n0  = (swz & 7) * 128;

    const int t    = threadIdx.x;
    const int lane = t & 63, wv = t >> 6;
    const int lr   = lane & 15, lg = lane >> 4;
    const int wr   = wv >> 1, wc = wv & 1;
    const int srow = wv * 32 + (lane >> 3);
    const int sseg = (lane & 7) * 8;

    f32x4 acc[4][4];
#pragma unroll
    for (int m = 0; m < 4; m++)
#pragma unroll
        for (int n = 0; n < 4; n++)
#pragma unroll
            for (int r = 0; r < 4; r++) acc[m][n][r] = 0.f;

    for (int kt = 0; kt < 16; kt++) {
        const int kk = kt * 64;
        __syncthreads();
#pragma unroll
        for (int i = 0; i < 4; i++) {
            int row = srow + i * 8;
            gload_lds16(&A [(size_t)(m0 + row) * 1024 + kk + sseg], &a_lds[row * 64 + sseg]);
            gload_lds16(&Bt[(size_t)(n0 + row) * 1024 + kk + sseg], &b_lds[row * 64 + sseg]);
        }
        __syncthreads();

        bf16x8 af[2][4], bf[2][4];
#pragma unroll
        for (int ks = 0; ks < 2; ks++) {
#pragma unroll
            for (int m = 0; m < 4; m++)
                af[ks][m] = *(const bf16x8*)&a_lds[(wr * 64 + m * 16 + lr) * 64 + ks * 32 + lg * 8];
#pragma unroll
            for (int n = 0; n < 4; n++)
                bf[ks][n] = *(const bf16x8*)&b_lds[(wc * 64 + n * 16 + lr) * 64 + ks * 32 + lg * 8];
        }
#pragma unroll
        for (int ks = 0; ks < 2; ks++)
#pragma unroll
            for (int m = 0; m < 4; m++)
#pragma unroll
                for (int n = 0; n < 4; n++)
                    acc[m][n] = __builtin_amdgcn_mfma_f32_16x16x32_bf16(af[ks][m], bf[ks][n], acc[m][n], 0, 0, 0);
    }

#pragma unroll
    for (int m = 0; m < 4; m++) {
#pragma unroll
        for (int n = 0; n < 4; n++) {
#pragma unroll
            for (int r = 0; r < 4; r++) {
                int row = m0 + wr * 64 + m * 16 + lg * 4 + r;
                int col = n0 + wc * 64 + n * 16 + lr;
                out[(size_t)row * HIDDEN + col] = acc[m][n][r] + bias[col];
            }
        }
    }
}

// ---------------------------------------------------------------------------
// Causal flash attention: 8 waves, 128 q-rows/block, KV tile 64, dbuf LDS.
// ---------------------------------------------------------------------------
__global__ __launch_bounds__(512) void attn_kernel(
    const u16* __restrict__ q_ws, const u16* __restrict__ k_ws,
    const u16* __restrict__ vt_ws, u16* __restrict__ ctx_ws)
{
    __shared__ u16 k_lds[2][64][72];   // [buf][kcol][d]
    __shared__ u16 vt_lds[2][64][72];  // [buf][d][kcol]
    __shared__ u16 p_lds[8][16][72];   // per-wave P bounce [qrow][kcol]

    const int t  = threadIdx.x;
    const int g  = blockIdx.x;
    // 1024 blocks = 64 bh x 16 q-tiles(128 rows). XCD-pinned: all 16 q-tiles
    // of a bh on one XCD (8 bh/XCD -> 4MB KV = L2). Long q-tiles first.
    const int bh  = ((g >> 7) << 3) | (g & 7);
    const int qt2 = 15 - ((g >> 3) & 15);

    const int lane = t & 63, wv = t >> 6;
    const int lr   = lane & 15, lg = lane >> 4;
    const int srow = t >> 3;           // 0..63 staging row
    const int sseg = (t & 7) * 8;      // staging col (8 u16 = 16B)

    const u16* kbase = k_ws  + (size_t)bh * SEQ * HEAD;
    const u16* vbase = vt_ws + (size_t)bh * HEAD * SEQ;

    // this wave's 16 q-rows (Q pre-scaled by 1/8)
    const int qr0 = qt2 * 128 + wv * 16;
    bf16x8 qa[2];
#pragma unroll
    for (int ks = 0; ks < 2; ks++)
        qa[ks] = *(const bf16x8*)&q_ws[((size_t)bh * SEQ + qr0 + lr) * HEAD + ks * 32 + lg * 8];

    // prologue: stage tile 0 into buffer 0
    {
        uint4 a0 = *(const uint4*)&kbase[(size_t)srow * HEAD + sseg];
        uint4 b0 = *(const uint4*)&vbase[(size_t)srow * SEQ + sseg];
        *(uint4*)&k_lds[0][srow][sseg]  = a0;
        *(uint4*)&vt_lds[0][srow][sseg] = b0;
    }
    __syncthreads();

    f32x4 acc_o[4];
#pragma unroll
    for (int df = 0; df < 4; df++)
#pragma unroll
        for (int r = 0; r < 4; r++) acc_o[df][r] = 0.f;
    float m_run[4], l_part[4];
#pragma unroll
    for (int r = 0; r < 4; r++) { m_run[r] = -3e38f; l_part[r] = 0.f; }

    int cur = 0;
    const int ktmax = 2 * qt2 + 1;
    for (int kt = 0; kt <= ktmax; kt++) {
        const bool pf = (kt < ktmax);
        uint4 kn, vn;
        if (pf) {  // issue next tile's loads early; latency hides under compute
            kn = *(const uint4*)&kbase[(size_t)((kt + 1) * 64 + srow) * HEAD + sseg];
            vn = *(const uint4*)&vbase[(size_t)srow * SEQ + (kt + 1) * 64 + sseg];
        }

        if (kt * 64 <= qr0 + 15) {   // wave has unmasked work in this tile
            // QK^T : S[16 q][64 k]
            f32x4 s_acc[4];
#pragma unroll
            for (int nf = 0; nf < 4; nf++) {
#pragma unroll
                for (int r = 0; r < 4; r++) s_acc[nf][r] = 0.f;
#pragma unroll
                for (int ks = 0; ks < 2; ks++) {
                    bf16x8 kb = *(const bf16x8*)&k_lds[cur][nf * 16 + lr][ks * 32 + lg * 8];
                    s_acc[nf] = __builtin_amdgcn_mfma_f32_16x16x32_bf16(qa[ks], kb, s_acc[nf], 0, 0, 0);
                }
            }

            if (kt * 64 + 63 > qr0) {  // tile touches/crosses diagonal: strict mask
#pragma unroll
                for (int nf = 0; nf < 4; nf++)
#pragma unroll
                    for (int r = 0; r < 4; r++) {
                        int gq = qr0 + lg * 4 + r;
                        int gk = kt * 64 + nf * 16 + lr;
                        if (gk > gq) s_acc[nf][r] = -1e9f;
                    }
            }

            // online softmax: tile-max via 16-lane reduce; row-sum deferred
            float p[4][4];
#pragma unroll
            for (int r = 0; r < 4; r++) {
                float mx = fmaxf(fmaxf(s_acc[0][r], s_acc[1][r]), fmaxf(s_acc[2][r], s_acc[3][r]));
#pragma unroll
                for (int off = 8; off >= 1; off >>= 1)
                    mx = fmaxf(mx, __shfl_xor(mx, off));
                float m_new = fmaxf(m_run[r], mx);
                float sc = __expf(m_run[r] - m_new);
                float rs;
                p[0][r] = __expf(s_acc[0][r] - m_new);
                p[1][r] = __expf(s_acc[1][r] - m_new);
                p[2][r] = __expf(s_acc[2][r] - m_new);
                p[3][r] = __expf(s_acc[3][r] - m_new);
                rs = (p[0][r] + p[1][r]) + (p[2][r] + p[3][r]);
                l_part[r] = l_part[r] * sc + rs;   // lane-partial; reduced at end
                m_run[r] = m_new;
#pragma unroll
                for (int df = 0; df < 4; df++) acc_o[df][r] *= sc;
            }

            // P bounce through per-wave LDS (wave-local; lgkmcnt ordering only)
#pragma unroll
            for (int nf = 0; nf < 4; nf++)
#pragma unroll
                for (int r = 0; r < 4; r++)
                    p_lds[wv][lg * 4 + r][nf * 16 + lr] = f2bf_n(p[nf][r]);

            bf16x8 pa[2];
#pragma unroll
            for (int ks = 0; ks < 2; ks++)
                pa[ks] = *(const bf16x8*)&p_lds[wv][lr][ks * 32 + lg * 8];

            // PV: O[16 q][64 d]
#pragma unroll
            for (int df = 0; df < 4; df++) {
#pragma unroll
                for (int ks = 0; ks < 2; ks++) {
                    bf16x8 vb = *(const bf16x8*)&vt_lds[cur][df * 16 + lr][ks * 32 + lg * 8];
                    acc_o[df] = __builtin_amdgcn_mfma_f32_16x16x32_bf16(pa[ks], vb, acc_o[df], 0, 0, 0);
                }
            }
        }

        if (pf) {
            const int nxt = cur ^ 1;
            *(uint4*)&k_lds[nxt][srow][sseg]  = kn;
            *(uint4*)&vt_lds[nxt][srow][sseg] = vn;
            __syncthreads();   // single barrier per tile
            cur = nxt;
        }
    }

    // final row-sum reduce (deferred from the loop)
    float inv[4];
#pragma unroll
    for (int r = 0; r < 4; r++) {
        float l = l_part[r];
#pragma unroll
        for (int off = 8; off >= 1; off >>= 1)
            l += __shfl_xor(l, off);
        inv[r] = 1.f / l;
    }

    // epilogue: ctx [B,S, h*64+d] bf16
    const int b = bh >> 4, h = bh & 15;
#pragma unroll
    for (int r = 0; r < 4; r++) {
        int s = qr0 + lg * 4 + r;
#pragma unroll
        for (int df = 0; df < 4; df++) {
            int d = df * 16 + lr;
            ctx_ws[((size_t)(b * SEQ + s)) * HIDDEN + h * HEAD + d] = f2bf_n(acc_o[df][r] * inv[r]);
        }
    }
}

// ---------------------------------------------------------------------------
extern "C" void kernel_launch(void* const* d_in, const int* in_sizes, int n_in,
                              void* d_out, int out_size, void* d_ws, size_t ws_size,
                              hipStream_t stream)
{
    const float* x    = (const float*)d_in[0];
    const float* qkvw = (const float*)d_in[1];
    const float* qkvb = (const float*)d_in[2];
    const float* outw = (const float*)d_in[3];
    const float* outb = (const float*)d_in[4];
    float* out = (float*)d_out;

    const size_t per = (size_t)BATCH * NHEADS * SEQ * HEAD; // 8388608 elems
    u16* q_ws   = (u16*)d_ws;
    u16* k_ws   = q_ws + per;
    u16* vt_ws  = k_ws + per;
    u16* c_ws   = vt_ws + per;
    u16* xb     = c_ws + per;
    u16* wqkvt  = xb + per;
    u16* wot    = wqkvt + (size_t)H3 * HIDDEN;

    conv_x <<<dim3((BS * HIDDEN) / (256 * 8)), 256, 0, stream>>>(x, xb);
    conv_wt<<<dim3(H3 / 64, HIDDEN / 64), 256, 0, stream>>>(qkvw, wqkvt, H3);
    conv_wt<<<dim3(HIDDEN / 64, HIDDEN / 64), 256, 0, stream>>>(outw, wot, HIDDEN);

    qkv_gemm<<<dim3(64 * 24), 256, 0, stream>>>(xb, wqkvt, qkvb, q_ws, k_ws, vt_ws);
    attn_kernel<<<dim3(64 * 16), 512, 0, stream>>>(q_ws, k_ws, vt_ws, c_ws);
    out_gemm<<<dim3(64 * 8), 256, 0, stream>>>(c_ws, wot, outb, out);
}